// Round 8
// baseline (396.889 us; speedup 1.0000x reference)
//
#include <hip/hip_runtime.h>
#include <cstdint>
#include <cstddef>

typedef unsigned int  uint;
typedef unsigned short ushort;
typedef short bf16x8 __attribute__((ext_vector_type(8)));
typedef float f32x4  __attribute__((ext_vector_type(4)));

#define N_NODES 50000
#define N_EDGES 1600000
#define N_META  3
#define DIM     128

#define BKT       128                 // dst nodes per bucket
#define NBKT      391                 // ceil(N_NODES / BKT)
#define BIN_CHUNK 4096
#define NCHUNK    391                 // ceil(N_EDGES / BIN_CHUNK)
#define CSR_CAP   5504                // bucket mean 4096, +22 sigma
#define OCH       128                 // out-degree edge chunks per metapath
#define EPC       (N_EDGES / OCH)     // 12500 edges per chunk
#define OWORDS    12500               // 50000 nodes / 4 per uint (byte-packed)
#define PREP_A    (N_META * OCH)      // 384 hist blocks
#define W1C_B     4                   // W1 fp32 -> bf16 transpose
#define CONV_B    64                  // h fp32 -> bf16 blocks

#define AT_TILE   64                  // attn: nodes per block (4 waves x 16)
#define AT_NBLK   782                 // ceil(N_NODES / AT_TILE)

__device__ __forceinline__ uint bf16rne(float f) {
    const uint u = __float_as_uint(f);
    return (u + 0x7FFFu + ((u >> 16) & 1u)) >> 16;
}
__device__ __forceinline__ float bflo(uint p) { return __uint_as_float(p << 16); }
__device__ __forceinline__ float bfhi(uint p) { return __uint_as_float(p & 0xFFFF0000u); }
__device__ __forceinline__ float fast_tanh(float x) {
    const float e = __expf(2.0f * x);
    return 1.0f - 2.0f / (e + 1.0f);
}

// ---------------------------------------------------------------------------
// K1: prep.
//   [0, PREP_A)      : (m, 12.5K-edge chunk): byte-packed src out-degree hist
//                      (50KB LDS) + dst bucket hist. uint4 edge reads.
//   [.., +W1C_B)     : W1 fp32 [k][j] -> W1T bf16 [j][k]
//   [.., +CONV_B)    : h fp32 -> hb bf16 (UNscaled -- one shared table; the
//                      per-metapath nsrc factor is applied per-edge in gather)
__global__ __launch_bounds__(256) void prep_kernel(
        const int* __restrict__ edges, const float* __restrict__ W1,
        const float* __restrict__ h, int* __restrict__ bucket_cnt,
        uint* __restrict__ partials, ushort* __restrict__ W1T,
        ushort* __restrict__ hb) {
    __shared__ __align__(16) uint sh[OWORDS];   // 50.0KB byte-packed out-degree
    __shared__ uint bh[NBKT];                   // bucket hist
    const int blk = blockIdx.x;
    if (blk < PREP_A) {
        const int m = blk >> 7, c = blk & 127;
        uint4* sh4 = reinterpret_cast<uint4*>(sh);
        for (int j = threadIdx.x; j < OWORDS / 4; j += 256)
            sh4[j] = make_uint4(0u, 0u, 0u, 0u);
        for (int j = threadIdx.x; j < NBKT; j += 256) bh[j] = 0;
        __syncthreads();
        const int* src = edges + (size_t)(2 * m) * N_EDGES;
        const int* dst = edges + (size_t)(2 * m + 1) * N_EDGES;
        const int beg = c * EPC;
        for (int i = beg + 4 * threadIdx.x; i + 4 <= beg + EPC; i += 1024) {
            const uint4 s4 = *reinterpret_cast<const uint4*>(src + i);
            const uint4 d4 = *reinterpret_cast<const uint4*>(dst + i);
            atomicAdd(&sh[s4.x >> 2], 1u << (8 * (s4.x & 3)));
            atomicAdd(&sh[s4.y >> 2], 1u << (8 * (s4.y & 3)));
            atomicAdd(&sh[s4.z >> 2], 1u << (8 * (s4.z & 3)));
            atomicAdd(&sh[s4.w >> 2], 1u << (8 * (s4.w & 3)));
            atomicAdd(&bh[d4.x >> 7], 1u);
            atomicAdd(&bh[d4.y >> 7], 1u);
            atomicAdd(&bh[d4.z >> 7], 1u);
            atomicAdd(&bh[d4.w >> 7], 1u);
        }
        __syncthreads();
        uint4* outp4 = reinterpret_cast<uint4*>(
            partials + (size_t)(m * OCH + c) * OWORDS);
        for (int j = threadIdx.x; j < OWORDS / 4; j += 256) outp4[j] = sh4[j];
        for (int j = threadIdx.x; j < NBKT; j += 256)
            if (bh[j]) atomicAdd(&bucket_cnt[m * NBKT + j], (int)bh[j]);
    } else if (blk < PREP_A + W1C_B) {
        // W1T[j][k] = bf16(W1[k][j]); writes coalesced, reads strided (L2-hot)
        const int base = (blk - PREP_A) * (DIM * DIM / W1C_B);
        for (int o = base + threadIdx.x; o < base + DIM * DIM / W1C_B; o += 256) {
            const int j = o >> 7, k = o & 127;
            W1T[o] = (ushort)bf16rne(W1[k * DIM + j]);
        }
    } else {
        const int b = blk - PREP_A - W1C_B;
        const int total = N_NODES * DIM / 4;           // float4 count
        for (int i = b * 256 + threadIdx.x; i < total; i += CONV_B * 256) {
            const float4 v = reinterpret_cast<const float4*>(h)[i];
            uint2 o;
            o.x = bf16rne(v.x) | (bf16rne(v.y) << 16);
            o.y = bf16rne(v.z) | (bf16rne(v.w) << 16);
            reinterpret_cast<uint2*>(hb)[i] = o;
        }
    }
}

// ---------------------------------------------------------------------------
// K2: bucket scan (512-thread Hillis-Steele over 391 buckets per m)
//     + nsrc = rsqrt(out_deg).
__global__ __launch_bounds__(512) void scan_nsrc_kernel(
        const int* __restrict__ bucket_cnt, int* __restrict__ bucket_off,
        int* __restrict__ bucket_cur, int* __restrict__ row_off,
        const uint* __restrict__ partials, float* __restrict__ nsrc) {
    const int blk = blockIdx.x;
    if (blk < N_META) {
        __shared__ int sc[512];
        const int m = blk, t = threadIdx.x;
        const int v = (t < NBKT) ? bucket_cnt[m * NBKT + t] : 0;
        sc[t] = v;
        __syncthreads();
        for (int off = 1; off < 512; off <<= 1) {
            const int tt = (t >= off) ? sc[t - off] : 0;
            __syncthreads();
            sc[t] += tt;
            __syncthreads();
        }
        const int excl = sc[t] - v;
        if (t < NBKT) {
            bucket_off[m * (NBKT + 1) + t] = excl;
            bucket_cur[m * NBKT + t] = excl;
        }
        if (t == 0) {
            bucket_off[m * (NBKT + 1) + NBKT] = N_EDGES;
            row_off[m * (N_NODES + 1) + N_NODES] = N_EDGES;
        }
    } else {
        const int i = (blk - N_META) * 512 + threadIdx.x;
        if (i < N_META * N_NODES) {
            const int m = i / N_NODES, node = i - m * N_NODES;
            const int q = node >> 2, s8 = 8 * (node & 3);
            int s = 0;
#pragma unroll 8
            for (int c = 0; c < OCH; ++c)
                s += (partials[(size_t)(m * OCH + c) * OWORDS + q] >> s8) & 0xFF;
            nsrc[i] = rsqrtf(fmaxf((float)s, 1.0f));
        }
    }
}

// ---------------------------------------------------------------------------
// K3: bin edges into dst-buckets as packed (dst<<16|src) pairs. uint4 reads.
__global__ __launch_bounds__(256) void bin_kernel(
        const int* __restrict__ edges, int* __restrict__ bucket_cur,
        uint* __restrict__ pairs) {
    const int m = blockIdx.y;
    __shared__ int hist[NBKT];
    __shared__ int cur[NBKT];
    for (int j = threadIdx.x; j < NBKT; j += 256) hist[j] = 0;
    __syncthreads();
    const int* src = edges + (size_t)(2 * m) * N_EDGES;
    const int* dst = edges + (size_t)(2 * m + 1) * N_EDGES;
    const int beg = blockIdx.x * BIN_CHUNK;
    const int end = min(beg + BIN_CHUNK, N_EDGES);
    // all chunk sizes (4096 and the 2560 tail) are multiples of 4
    for (int i = beg + 4 * threadIdx.x; i + 4 <= end; i += 1024) {
        const uint4 d4 = *reinterpret_cast<const uint4*>(dst + i);
        atomicAdd(&hist[d4.x >> 7], 1);
        atomicAdd(&hist[d4.y >> 7], 1);
        atomicAdd(&hist[d4.z >> 7], 1);
        atomicAdd(&hist[d4.w >> 7], 1);
    }
    __syncthreads();
    for (int j = threadIdx.x; j < NBKT; j += 256) {
        const int n = hist[j];
        cur[j] = n ? atomicAdd(&bucket_cur[m * NBKT + j], n) : 0;
    }
    __syncthreads();
    uint* pm = pairs + (size_t)m * N_EDGES;
    for (int i = beg + 4 * threadIdx.x; i + 4 <= end; i += 1024) {
        const uint4 s4 = *reinterpret_cast<const uint4*>(src + i);
        const uint4 d4 = *reinterpret_cast<const uint4*>(dst + i);
        int p0 = atomicAdd(&cur[d4.x >> 7], 1);
        pm[p0] = (d4.x << 16) | s4.x;
        int p1 = atomicAdd(&cur[d4.y >> 7], 1);
        pm[p1] = (d4.y << 16) | s4.y;
        int p2 = atomicAdd(&cur[d4.z >> 7], 1);
        pm[p2] = (d4.z << 16) | s4.z;
        int p3 = atomicAdd(&cur[d4.w >> 7], 1);
        pm[p3] = (d4.w << 16) | s4.w;
    }
}

// ---------------------------------------------------------------------------
// K4: finalize CSR per bucket (ushort src ids). 128-node buckets, 128 threads.
__global__ __launch_bounds__(128) void csr_kernel(
        const uint* __restrict__ pairs, const int* __restrict__ bucket_off,
        int* __restrict__ row_off, ushort* __restrict__ csr) {
    const int b = blockIdx.x, m = blockIdx.y;
    const int node_base = b * BKT;
    const int nb = min(BKT, N_NODES - node_base);
    __shared__ uint stage[CSR_CAP];
    __shared__ int hist[BKT];
    __shared__ int sc[BKT];
    __shared__ int cur[BKT];
    hist[threadIdx.x] = 0;
    __syncthreads();
    const int beg = bucket_off[m * (NBKT + 1) + b];
    const int end = bucket_off[m * (NBKT + 1) + b + 1];
    const int cnt = end - beg;
    const uint* pm = pairs + (size_t)m * N_EDGES + beg;
    for (int i = threadIdx.x; i < cnt; i += 128) {
        const uint p = pm[i];
        if (i < CSR_CAP) stage[i] = p;
        atomicAdd(&hist[(int)(p >> 16) - node_base], 1);
    }
    __syncthreads();
    const int v = hist[threadIdx.x];
    sc[threadIdx.x] = v;
    __syncthreads();
    for (int off = 1; off < BKT; off <<= 1) {
        const int t = (threadIdx.x >= off) ? sc[threadIdx.x - off] : 0;
        __syncthreads();
        sc[threadIdx.x] += t;
        __syncthreads();
    }
    const int excl = sc[threadIdx.x] - v;
    cur[threadIdx.x] = beg + excl;
    if (threadIdx.x < nb)
        row_off[m * (N_NODES + 1) + node_base + threadIdx.x] = beg + excl;
    __syncthreads();
    ushort* cm = csr + (size_t)m * N_EDGES;
    for (int i = threadIdx.x; i < cnt; i += 128) {
        const uint p = (i < CSR_CAP) ? stage[i] : pm[i];
        const int dl = (int)(p >> 16) - node_base;
        const int pos = atomicAdd(&cur[dl], 1);
        cm[pos] = (ushort)(p & 0xFFFFu);
    }
}

// ---------------------------------------------------------------------------
// K5: gather. One wave per dst node; quarter-wave (16 lanes x uint4 = 256B)
// covers a full bf16 row, 4 edges/step, unroll-4 -> 16 edges in flight.
// SINGLE shared hb table (12.8MB, 3x smaller working set than pre-scaled);
// per-edge nsrc applied via fmaf (same VALU op count as plain add).
__global__ __launch_bounds__(256) void gather_kernel(
        const ushort* __restrict__ hb, const ushort* __restrict__ csr,
        const int* __restrict__ row_off, const float* __restrict__ nsrc,
        ushort* __restrict__ zb) {
    const int m    = blockIdx.y;
    const int wave = threadIdx.x >> 6;
    const int lane = threadIdx.x & 63;
    const int q    = lane >> 4;              // edge slot 0..3
    const int c16  = lane & 15;              // dims 8*c16 .. 8*c16+7
    const int node = blockIdx.x * 4 + wave;
    const int* ro = row_off + m * (N_NODES + 1);
    const int beg = ro[node];
    const int end = ro[node + 1];
    const ushort* srcs = csr + (size_t)m * N_EDGES;
    const float* ns = nsrc + m * N_NODES;
    float acc[8] = {};
    int j = beg;
    for (; j + 16 <= end; j += 16) {
        int s[4]; float n[4]; uint4 hv[4];
#pragma unroll
        for (int u = 0; u < 4; ++u) s[u] = srcs[j + 4 * u + q];
#pragma unroll
        for (int u = 0; u < 4; ++u) {
            n[u]  = ns[s[u]];
            hv[u] = *reinterpret_cast<const uint4*>(hb + (size_t)s[u] * DIM + c16 * 8);
        }
#pragma unroll
        for (int u = 0; u < 4; ++u) {
            acc[0] = fmaf(bflo(hv[u].x), n[u], acc[0]);
            acc[1] = fmaf(bfhi(hv[u].x), n[u], acc[1]);
            acc[2] = fmaf(bflo(hv[u].y), n[u], acc[2]);
            acc[3] = fmaf(bfhi(hv[u].y), n[u], acc[3]);
            acc[4] = fmaf(bflo(hv[u].z), n[u], acc[4]);
            acc[5] = fmaf(bfhi(hv[u].z), n[u], acc[5]);
            acc[6] = fmaf(bflo(hv[u].w), n[u], acc[6]);
            acc[7] = fmaf(bfhi(hv[u].w), n[u], acc[7]);
        }
    }
    for (; j + 4 <= end; j += 4) {
        const int s0 = srcs[j + q];
        const float n0 = ns[s0];
        const uint4 hv = *reinterpret_cast<const uint4*>(hb + (size_t)s0 * DIM + c16 * 8);
        acc[0] = fmaf(bflo(hv.x), n0, acc[0]);
        acc[1] = fmaf(bfhi(hv.x), n0, acc[1]);
        acc[2] = fmaf(bflo(hv.y), n0, acc[2]);
        acc[3] = fmaf(bfhi(hv.y), n0, acc[3]);
        acc[4] = fmaf(bflo(hv.z), n0, acc[4]);
        acc[5] = fmaf(bfhi(hv.z), n0, acc[5]);
        acc[6] = fmaf(bflo(hv.w), n0, acc[6]);
        acc[7] = fmaf(bfhi(hv.w), n0, acc[7]);
    }
    if (j + q < end) {
        const int s0 = srcs[j + q];
        const float n0 = ns[s0];
        const uint4 hv = *reinterpret_cast<const uint4*>(hb + (size_t)s0 * DIM + c16 * 8);
        acc[0] = fmaf(bflo(hv.x), n0, acc[0]);
        acc[1] = fmaf(bfhi(hv.x), n0, acc[1]);
        acc[2] = fmaf(bflo(hv.y), n0, acc[2]);
        acc[3] = fmaf(bfhi(hv.y), n0, acc[3]);
        acc[4] = fmaf(bflo(hv.z), n0, acc[4]);
        acc[5] = fmaf(bfhi(hv.z), n0, acc[5]);
        acc[6] = fmaf(bflo(hv.w), n0, acc[6]);
        acc[7] = fmaf(bfhi(hv.w), n0, acc[7]);
    }
#pragma unroll
    for (int k = 0; k < 8; ++k) {
        acc[k] += __shfl_xor(acc[k], 16);
        acc[k] += __shfl_xor(acc[k], 32);
    }
    if (lane < 16) {
        const float nd = rsqrtf(fmaxf((float)(end - beg), 1.0f));
        uint4 o;
        o.x = bf16rne(acc[0] * nd) | (bf16rne(acc[1] * nd) << 16);
        o.y = bf16rne(acc[2] * nd) | (bf16rne(acc[3] * nd) << 16);
        o.z = bf16rne(acc[4] * nd) | (bf16rne(acc[5] * nd) << 16);
        o.w = bf16rne(acc[6] * nd) | (bf16rne(acc[7] * nd) << 16);
        *reinterpret_cast<uint4*>(
            zb + ((size_t)m * N_NODES + node) * DIM + c16 * 8) = o;
    }
}

// ---------------------------------------------------------------------------
// K6: semantic attention via MFMA (16x16x32 bf16). A-frags straight from
// global; B-frags from XOR-swizzled LDS W1T. C: col=lane&15, row=(lane>>4)*4+r.
__global__ __launch_bounds__(256) void attn_kernel(
        const ushort* __restrict__ zb, const ushort* __restrict__ W1T,
        const float* __restrict__ b1, const float* __restrict__ W2,
        float* __restrict__ wacc) {
    const int m   = blockIdx.y;
    const int tid = threadIdx.x;
    const int wv  = tid >> 6;
    const int l   = tid & 63;
    __shared__ __align__(16) ushort w1s[DIM * DIM];   // swizzled [j][k] bf16
    __shared__ float red[4];

    {   // stage W1T with XOR swizzle on the 16B-slot index
        const uint4* g = reinterpret_cast<const uint4*>(W1T);
        for (int i = tid; i < DIM * DIM / 8; i += 256) {
            const int j = i >> 4;                      // 16 uint4 per j-row
            const int slot = i ^ (j & 7);
            *reinterpret_cast<uint4*>(
                reinterpret_cast<char*>(w1s) + slot * 16) = g[i];
        }
    }
    __syncthreads();

    const int node_base = blockIdx.x * AT_TILE + wv * 16;
    const int row = l & 15;                // node within tile / j within tile
    const int q   = l >> 4;                // k-chunk / C row-quad
    int nload = node_base + row;
    if (nload >= N_NODES) nload = N_NODES - 1;         // clamp; masked later
    const ushort* zrow = zb + ((size_t)m * N_NODES + nload) * DIM + q * 8;

    bf16x8 a[4];
#pragma unroll
    for (int kk = 0; kk < 4; ++kk)
        a[kk] = *reinterpret_cast<const bf16x8*>(zrow + kk * 32);

    f32x4 acc[8];
#pragma unroll
    for (int ct = 0; ct < 8; ++ct) acc[ct] = (f32x4){0.f, 0.f, 0.f, 0.f};

#pragma unroll
    for (int kk = 0; kk < 4; ++kk) {
#pragma unroll
        for (int ct = 0; ct < 8; ++ct) {
            const int j = ct * 16 + row;
            const int slot = (j * 16 + kk * 4 + q) ^ (j & 7);
            const bf16x8 b = *reinterpret_cast<const bf16x8*>(
                reinterpret_cast<char*>(w1s) + slot * 16);
            acc[ct] = __builtin_amdgcn_mfma_f32_16x16x32_bf16(
                a[kk], b, acc[ct], 0, 0, 0);
        }
    }

    float local = 0.0f;
#pragma unroll
    for (int ct = 0; ct < 8; ++ct) {
        const int j = ct * 16 + row;
        const float b1j = b1[j];
        const float w2j = W2[j];
#pragma unroll
        for (int r = 0; r < 4; ++r) {
            const int nd = node_base + q * 4 + r;
            if (nd < N_NODES)
                local += fast_tanh(acc[ct][r] + b1j) * w2j;
        }
    }
    for (int off = 32; off > 0; off >>= 1)
        local += __shfl_xor(local, off);
    if (l == 0) red[wv] = local;
    __syncthreads();
    if (tid == 0)
        atomicAdd(&wacc[m], red[0] + red[1] + red[2] + red[3]);
}

// ---------------------------------------------------------------------------
// K7: softmax over 3 scores + beta-weighted sum (bf16 z -> fp32 out).
__global__ __launch_bounds__(256) void final_kernel(
        const ushort* __restrict__ zb, const float* __restrict__ wacc,
        float* __restrict__ out) {
    const int g = blockIdx.x * 256 + threadIdx.x;      // 8-dim group, exact grid
    const float invN = 1.0f / (float)N_NODES;
    const float w0 = wacc[0] * invN, w1 = wacc[1] * invN, w2 = wacc[2] * invN;
    const float mx = fmaxf(w0, fmaxf(w1, w2));
    const float e0 = expf(w0 - mx), e1 = expf(w1 - mx), e2 = expf(w2 - mx);
    const float inv = 1.0f / (e0 + e1 + e2);
    const float beta[3] = {e0 * inv, e1 * inv, e2 * inv};
    float a[8] = {};
#pragma unroll
    for (int m = 0; m < N_META; ++m) {
        const uint4 v = reinterpret_cast<const uint4*>(zb)[
            (size_t)m * (N_NODES * DIM / 8) + g];
        const float bm = beta[m];
        a[0] = fmaf(bflo(v.x), bm, a[0]); a[1] = fmaf(bfhi(v.x), bm, a[1]);
        a[2] = fmaf(bflo(v.y), bm, a[2]); a[3] = fmaf(bfhi(v.y), bm, a[3]);
        a[4] = fmaf(bflo(v.z), bm, a[4]); a[5] = fmaf(bfhi(v.z), bm, a[5]);
        a[6] = fmaf(bflo(v.w), bm, a[6]); a[7] = fmaf(bfhi(v.w), bm, a[7]);
    }
    float4 o0 = {a[0], a[1], a[2], a[3]};
    float4 o1 = {a[4], a[5], a[6], a[7]};
    reinterpret_cast<float4*>(out)[(size_t)g * 2 + 0] = o0;
    reinterpret_cast<float4*>(out)[(size_t)g * 2 + 1] = o1;
}

extern "C" void kernel_launch(void* const* d_in, const int* in_sizes, int n_in,
                              void* d_out, int out_size, void* d_ws, size_t ws_size,
                              hipStream_t stream) {
    const float* h    = (const float*)d_in[0];
    const int*  edges = (const int*)d_in[1];
    const float* W1   = (const float*)d_in[2];
    const float* b1   = (const float*)d_in[3];
    const float* W2   = (const float*)d_in[4];
    float* out = (float*)d_out;

    // ws (~62MB): zb bf16 [38.4MB] region hosts pairs[19.2MB]+partials[19.2MB]
    // early (both dead before gather writes zb) | hb (ONE shared bf16 table,
    // 12.8MB) | csr | row_off | nsrc | small
    char* p = (char*)d_ws;
    ushort* zb      = (ushort*)p;
    uint*  pairs    = (uint*)p;
    uint*  partials = (uint*)(p + (size_t)N_META * N_EDGES * 4);
    p += (size_t)N_META * N_NODES * DIM * 2;
    ushort* hb      = (ushort*)p; p += (size_t)N_NODES * DIM * 2;
    ushort* csr     = (ushort*)p; p += (size_t)N_META * N_EDGES * 2;
    int* row_off    = (int*)p;    p += ((size_t)N_META * (N_NODES + 1) + 1) * 4;
    float* nsrc     = (float*)p;  p += (size_t)N_META * N_NODES * 4;
    float* wacc     = (float*)p;  p += 16 * 4;
    int* bucket_cnt = (int*)p;    p += (size_t)N_META * NBKT * 4;
    int* bucket_off = (int*)p;    p += (size_t)N_META * (NBKT + 1) * 4 + 4;
    int* bucket_cur = (int*)p;    p += (size_t)N_META * NBKT * 4;
    ushort* W1T     = (ushort*)p; p += (size_t)DIM * DIM * 2;

    // zero wacc + bucket_cnt (contiguous)
    hipMemsetAsync(wacc, 0, (16 + (size_t)N_META * NBKT) * 4, stream);

    prep_kernel<<<dim3(PREP_A + W1C_B + CONV_B), 256, 0, stream>>>(
        edges, W1, h, bucket_cnt, partials, W1T, hb);
    scan_nsrc_kernel<<<dim3(N_META + (N_META * N_NODES + 511) / 512), 512, 0, stream>>>(
        bucket_cnt, bucket_off, bucket_cur, row_off, partials, nsrc);
    bin_kernel<<<dim3(NCHUNK, N_META), 256, 0, stream>>>(edges, bucket_cur, pairs);
    csr_kernel<<<dim3(NBKT, N_META), 128, 0, stream>>>(pairs, bucket_off, row_off, csr);
    gather_kernel<<<dim3(N_NODES / 4, N_META), 256, 0, stream>>>(
        hb, csr, row_off, nsrc, zb);
    attn_kernel<<<dim3(AT_NBLK, N_META), 256, 0, stream>>>(zb, W1T, b1, W2, wacc);
    final_kernel<<<dim3(N_NODES * DIM / 8 / 256), 256, 0, stream>>>(zb, wacc, out);
}

// Round 9
// 381.920 us; speedup vs baseline: 1.0392x; 1.0392x over previous
//
#include <hip/hip_runtime.h>
#include <cstdint>
#include <cstddef>

typedef unsigned int  uint;
typedef unsigned short ushort;
typedef short bf16x8 __attribute__((ext_vector_type(8)));
typedef float f32x4  __attribute__((ext_vector_type(4)));

#define N_NODES 50000
#define N_EDGES 1600000
#define N_META  3
#define DIM     128

#define BKT       256                 // dst nodes per bucket
#define NBKT      196                 // ceil(N_NODES / BKT)
#define CSR_CAP   10240               // bucket mean 8192, +22 sigma
#define OCH       128                 // edge chunks per metapath
#define EPC       (N_EDGES / OCH)     // 12500 edges per chunk
#define OWORDS    12500               // 50000 nodes / 4 per uint (byte-packed)
#define PREP_A    (N_META * OCH)      // 384 hist blocks
#define W1C_B     4                   // W1 fp32 -> bf16 transpose

#define AT_TILE   64                  // attn: nodes per block (4 waves x 16)
#define AT_NBLK   782                 // ceil(N_NODES / AT_TILE)

__device__ __forceinline__ uint bf16rne(float f) {
    const uint u = __float_as_uint(f);
    return (u + 0x7FFFu + ((u >> 16) & 1u)) >> 16;
}
__device__ __forceinline__ float bflo(uint p) { return __uint_as_float(p << 16); }
__device__ __forceinline__ float bfhi(uint p) { return __uint_as_float(p & 0xFFFF0000u); }
__device__ __forceinline__ float fast_tanh(float x) {
    const float e = __expf(2.0f * x);
    return 1.0f - 2.0f / (e + 1.0f);
}

// ---------------------------------------------------------------------------
// K1: prep.
//   [0, PREP_A)   : block = (m, chunk of 12.5K edges). Byte-packed src
//                   out-degree hist (50KB LDS) + dst bucket hist. The bucket
//                   hist is STORED per (m,chunk) (not atomically merged) so
//                   bin's first pass can be deleted entirely.
//   [.., +W1C_B)  : W1 fp32 [k][j] -> W1T bf16 [j][k]
__global__ __launch_bounds__(256) void prep_kernel(
        const int* __restrict__ edges, const float* __restrict__ W1,
        uint* __restrict__ bhout, uint* __restrict__ partials,
        ushort* __restrict__ W1T) {
    __shared__ __align__(16) uint sh[OWORDS];   // 50.0KB byte-packed out-degree
    __shared__ uint bh[NBKT];                   // bucket hist
    const int blk = blockIdx.x;
    if (blk < PREP_A) {
        const int m = blk >> 7, c = blk & 127;
        uint4* sh4 = reinterpret_cast<uint4*>(sh);
        for (int j = threadIdx.x; j < OWORDS / 4; j += 256)
            sh4[j] = make_uint4(0u, 0u, 0u, 0u);
        for (int j = threadIdx.x; j < NBKT; j += 256) bh[j] = 0;
        __syncthreads();
        const int* src = edges + (size_t)(2 * m) * N_EDGES;
        const int* dst = edges + (size_t)(2 * m + 1) * N_EDGES;
        const int beg = c * EPC;
        for (int i = beg + 4 * threadIdx.x; i + 4 <= beg + EPC; i += 1024) {
            const uint4 s4 = *reinterpret_cast<const uint4*>(src + i);
            const uint4 d4 = *reinterpret_cast<const uint4*>(dst + i);
            atomicAdd(&sh[s4.x >> 2], 1u << (8 * (s4.x & 3)));
            atomicAdd(&sh[s4.y >> 2], 1u << (8 * (s4.y & 3)));
            atomicAdd(&sh[s4.z >> 2], 1u << (8 * (s4.z & 3)));
            atomicAdd(&sh[s4.w >> 2], 1u << (8 * (s4.w & 3)));
            atomicAdd(&bh[d4.x >> 8], 1u);
            atomicAdd(&bh[d4.y >> 8], 1u);
            atomicAdd(&bh[d4.z >> 8], 1u);
            atomicAdd(&bh[d4.w >> 8], 1u);
        }
        __syncthreads();
        uint4* outp4 = reinterpret_cast<uint4*>(
            partials + (size_t)(m * OCH + c) * OWORDS);
        for (int j = threadIdx.x; j < OWORDS / 4; j += 256) outp4[j] = sh4[j];
        uint* bo = bhout + (size_t)(m * OCH + c) * NBKT;
        for (int j = threadIdx.x; j < NBKT; j += 256) bo[j] = bh[j];
    } else {
        // W1T[j][k] = bf16(W1[k][j]); writes coalesced, reads strided (L2-hot)
        const int base = (blk - PREP_A) * (DIM * DIM / W1C_B);
        for (int o = base + threadIdx.x; o < base + DIM * DIM / W1C_B; o += 256) {
            const int j = o >> 7, k = o & 127;
            W1T[o] = (ushort)bf16rne(W1[k * DIM + j]);
        }
    }
}

// ---------------------------------------------------------------------------
// K2: scan.
//   [0, N_META)   : per-m: bucket totals (column sums of bh), Hillis-Steele
//                   prefix -> bucket_off, then per-chunk base table
//                   chunk_base[m][c][b] so bin needs NO histogram pass.
//   [N_META, ..)  : nsrc = rsqrt(out_deg) from byte-packed partials.
__global__ __launch_bounds__(256) void scan_nsrc_kernel(
        const uint* __restrict__ bhout, int* __restrict__ bucket_off,
        int* __restrict__ chunk_base, int* __restrict__ row_off,
        const uint* __restrict__ partials, float* __restrict__ nsrc) {
    const int blk = blockIdx.x;
    if (blk < N_META) {
        __shared__ int sc[256];
        const int m = blk, t = threadIdx.x;
        int v = 0;
        if (t < NBKT)
            for (int c = 0; c < OCH; ++c)
                v += (int)bhout[(size_t)(m * OCH + c) * NBKT + t];
        sc[t] = v;
        __syncthreads();
        for (int off = 1; off < 256; off <<= 1) {
            const int tt = (t >= off) ? sc[t - off] : 0;
            __syncthreads();
            sc[t] += tt;
            __syncthreads();
        }
        const int excl = sc[t] - v;
        if (t < NBKT) {
            bucket_off[m * (NBKT + 1) + t] = excl;
            int run = excl;
            for (int c = 0; c < OCH; ++c) {
                chunk_base[(size_t)(m * OCH + c) * NBKT + t] = run;
                run += (int)bhout[(size_t)(m * OCH + c) * NBKT + t];
            }
        }
        if (t == 0) {
            bucket_off[m * (NBKT + 1) + NBKT] = N_EDGES;
            row_off[m * (N_NODES + 1) + N_NODES] = N_EDGES;
        }
    } else {
        const int i = (blk - N_META) * 256 + threadIdx.x;
        if (i < N_META * N_NODES) {
            const int m = i / N_NODES, node = i - m * N_NODES;
            const int q = node >> 2, s8 = 8 * (node & 3);
            int s = 0;
#pragma unroll 8
            for (int c = 0; c < OCH; ++c)
                s += (partials[(size_t)(m * OCH + c) * OWORDS + q] >> s8) & 0xFF;
            nsrc[i] = rsqrtf(fmaxf((float)s, 1.0f));
        }
    }
}

// ---------------------------------------------------------------------------
// K3: premultiplied tables hbm[m][n][d] = bf16(h[n][d] * nsrc[m][n]).
__global__ __launch_bounds__(256) void scale_kernel(
        const float* __restrict__ h, const float* __restrict__ nsrc,
        ushort* __restrict__ hbm) {
    const int i = blockIdx.x * 256 + threadIdx.x;   // float4 index, exact grid
    const int node = i >> 5;                        // DIM/4 = 32 float4 per row
    const float4 v = reinterpret_cast<const float4*>(h)[i];
    uint2* o = reinterpret_cast<uint2*>(hbm);
#pragma unroll
    for (int m = 0; m < N_META; ++m) {
        const float n = nsrc[m * N_NODES + node];
        uint2 p;
        p.x = bf16rne(v.x * n) | (bf16rne(v.y * n) << 16);
        p.y = bf16rne(v.z * n) | (bf16rne(v.w * n) << 16);
        o[(size_t)m * (N_NODES * DIM / 4) + i] = p;
    }
}

// ---------------------------------------------------------------------------
// K4: bin = single scatter pass. Cursors come precomputed from chunk_base
// (no histogram pass, no global atomics). Packed (dst<<16|src) pairs.
__global__ __launch_bounds__(256) void bin_kernel(
        const int* __restrict__ edges, const int* __restrict__ chunk_base,
        uint* __restrict__ pairs) {
    const int m = blockIdx.y, c = blockIdx.x;
    __shared__ int cur[NBKT];
    const int* cb = chunk_base + (size_t)(m * OCH + c) * NBKT;
    for (int j = threadIdx.x; j < NBKT; j += 256) cur[j] = cb[j];
    __syncthreads();
    const int* src = edges + (size_t)(2 * m) * N_EDGES;
    const int* dst = edges + (size_t)(2 * m + 1) * N_EDGES;
    const int beg = c * EPC;
    uint* pm = pairs + (size_t)m * N_EDGES;
    for (int i = beg + 4 * threadIdx.x; i + 4 <= beg + EPC; i += 1024) {
        const uint4 s4 = *reinterpret_cast<const uint4*>(src + i);
        const uint4 d4 = *reinterpret_cast<const uint4*>(dst + i);
        int p0 = atomicAdd(&cur[d4.x >> 8], 1);
        pm[p0] = (d4.x << 16) | s4.x;
        int p1 = atomicAdd(&cur[d4.y >> 8], 1);
        pm[p1] = (d4.y << 16) | s4.y;
        int p2 = atomicAdd(&cur[d4.z >> 8], 1);
        pm[p2] = (d4.z << 16) | s4.z;
        int p3 = atomicAdd(&cur[d4.w >> 8], 1);
        pm[p3] = (d4.w << 16) | s4.w;
    }
}

// ---------------------------------------------------------------------------
// K5: finalize CSR per bucket (ushort src ids).
__global__ __launch_bounds__(256) void csr_kernel(
        const uint* __restrict__ pairs, const int* __restrict__ bucket_off,
        int* __restrict__ row_off, ushort* __restrict__ csr) {
    const int b = blockIdx.x, m = blockIdx.y;
    const int node_base = b * BKT;
    const int nb = min(BKT, N_NODES - node_base);
    __shared__ uint stage[CSR_CAP];
    __shared__ int hist[BKT];
    __shared__ int sc[BKT];
    __shared__ int cur[BKT];
    hist[threadIdx.x] = 0;
    __syncthreads();
    const int beg = bucket_off[m * (NBKT + 1) + b];
    const int end = bucket_off[m * (NBKT + 1) + b + 1];
    const int cnt = end - beg;
    const uint* pm = pairs + (size_t)m * N_EDGES + beg;
    for (int i = threadIdx.x; i < cnt; i += 256) {
        const uint p = pm[i];
        if (i < CSR_CAP) stage[i] = p;
        atomicAdd(&hist[(int)(p >> 16) - node_base], 1);
    }
    __syncthreads();
    const int v = hist[threadIdx.x];
    sc[threadIdx.x] = v;
    __syncthreads();
    for (int off = 1; off < BKT; off <<= 1) {
        const int t = (threadIdx.x >= off) ? sc[threadIdx.x - off] : 0;
        __syncthreads();
        sc[threadIdx.x] += t;
        __syncthreads();
    }
    const int excl = sc[threadIdx.x] - v;
    cur[threadIdx.x] = beg + excl;
    if (threadIdx.x < nb)
        row_off[m * (N_NODES + 1) + node_base + threadIdx.x] = beg + excl;
    __syncthreads();
    ushort* cm = csr + (size_t)m * N_EDGES;
    for (int i = threadIdx.x; i < cnt; i += 256) {
        const uint p = (i < CSR_CAP) ? stage[i] : pm[i];
        const int dl = (int)(p >> 16) - node_base;
        const int pos = atomicAdd(&cur[dl], 1);
        cm[pos] = (ushort)(p & 0xFFFFu);
    }
}

// ---------------------------------------------------------------------------
// K6: gather. One wave per dst node; quarter-wave (16 lanes x uint4 = 256B)
// covers a full bf16 row, 4 edges/step, unroll-4 -> 16 edges in flight.
// Rows are pre-scaled by nsrc, so the loop is pure load+add. z stored bf16.
__global__ __launch_bounds__(256) void gather_kernel(
        const ushort* __restrict__ hbm, const ushort* __restrict__ csr,
        const int* __restrict__ row_off, ushort* __restrict__ zb) {
    const int m    = blockIdx.y;
    const int wave = threadIdx.x >> 6;
    const int lane = threadIdx.x & 63;
    const int q    = lane >> 4;              // edge slot 0..3
    const int c16  = lane & 15;              // dims 8*c16 .. 8*c16+7
    const int node = blockIdx.x * 4 + wave;
    const int* ro = row_off + m * (N_NODES + 1);
    const int beg = ro[node];
    const int end = ro[node + 1];
    const ushort* srcs = csr + (size_t)m * N_EDGES;
    const ushort* tab  = hbm + (size_t)m * N_NODES * DIM;
    float acc[8] = {};
    int j = beg;
    for (; j + 16 <= end; j += 16) {
        int s[4]; uint4 hv[4];
#pragma unroll
        for (int u = 0; u < 4; ++u) s[u] = srcs[j + 4 * u + q];
#pragma unroll
        for (int u = 0; u < 4; ++u)
            hv[u] = *reinterpret_cast<const uint4*>(tab + (size_t)s[u] * DIM + c16 * 8);
#pragma unroll
        for (int u = 0; u < 4; ++u) {
            acc[0] += bflo(hv[u].x); acc[1] += bfhi(hv[u].x);
            acc[2] += bflo(hv[u].y); acc[3] += bfhi(hv[u].y);
            acc[4] += bflo(hv[u].z); acc[5] += bfhi(hv[u].z);
            acc[6] += bflo(hv[u].w); acc[7] += bfhi(hv[u].w);
        }
    }
    for (; j + 4 <= end; j += 4) {
        const int s0 = srcs[j + q];
        const uint4 hv = *reinterpret_cast<const uint4*>(tab + (size_t)s0 * DIM + c16 * 8);
        acc[0] += bflo(hv.x); acc[1] += bfhi(hv.x);
        acc[2] += bflo(hv.y); acc[3] += bfhi(hv.y);
        acc[4] += bflo(hv.z); acc[5] += bfhi(hv.z);
        acc[6] += bflo(hv.w); acc[7] += bfhi(hv.w);
    }
    if (j + q < end) {
        const int s0 = srcs[j + q];
        const uint4 hv = *reinterpret_cast<const uint4*>(tab + (size_t)s0 * DIM + c16 * 8);
        acc[0] += bflo(hv.x); acc[1] += bfhi(hv.x);
        acc[2] += bflo(hv.y); acc[3] += bfhi(hv.y);
        acc[4] += bflo(hv.z); acc[5] += bfhi(hv.z);
        acc[6] += bflo(hv.w); acc[7] += bfhi(hv.w);
    }
#pragma unroll
    for (int k = 0; k < 8; ++k) {
        acc[k] += __shfl_xor(acc[k], 16);
        acc[k] += __shfl_xor(acc[k], 32);
    }
    if (lane < 16) {
        const float nd = rsqrtf(fmaxf((float)(end - beg), 1.0f));
        uint4 o;
        o.x = bf16rne(acc[0] * nd) | (bf16rne(acc[1] * nd) << 16);
        o.y = bf16rne(acc[2] * nd) | (bf16rne(acc[3] * nd) << 16);
        o.z = bf16rne(acc[4] * nd) | (bf16rne(acc[5] * nd) << 16);
        o.w = bf16rne(acc[6] * nd) | (bf16rne(acc[7] * nd) << 16);
        *reinterpret_cast<uint4*>(
            zb + ((size_t)m * N_NODES + node) * DIM + c16 * 8) = o;
    }
}

// ---------------------------------------------------------------------------
// K7: semantic attention via MFMA (16x16x32 bf16). A-frags straight from
// global; B-frags from XOR-swizzled LDS W1T. C: col=lane&15, row=(lane>>4)*4+r.
__global__ __launch_bounds__(256) void attn_kernel(
        const ushort* __restrict__ zb, const ushort* __restrict__ W1T,
        const float* __restrict__ b1, const float* __restrict__ W2,
        float* __restrict__ wacc) {
    const int m   = blockIdx.y;
    const int tid = threadIdx.x;
    const int wv  = tid >> 6;
    const int l   = tid & 63;
    __shared__ __align__(16) ushort w1s[DIM * DIM];   // swizzled [j][k] bf16
    __shared__ float red[4];

    {   // stage W1T with XOR swizzle on the 16B-slot index
        const uint4* g = reinterpret_cast<const uint4*>(W1T);
        for (int i = tid; i < DIM * DIM / 8; i += 256) {
            const int j = i >> 4;                      // 16 uint4 per j-row
            const int slot = i ^ (j & 7);
            *reinterpret_cast<uint4*>(
                reinterpret_cast<char*>(w1s) + slot * 16) = g[i];
        }
    }
    __syncthreads();

    const int node_base = blockIdx.x * AT_TILE + wv * 16;
    const int row = l & 15;                // node within tile / j within tile
    const int q   = l >> 4;                // k-chunk / C row-quad
    int nload = node_base + row;
    if (nload >= N_NODES) nload = N_NODES - 1;         // clamp; masked later
    const ushort* zrow = zb + ((size_t)m * N_NODES + nload) * DIM + q * 8;

    bf16x8 a[4];
#pragma unroll
    for (int kk = 0; kk < 4; ++kk)
        a[kk] = *reinterpret_cast<const bf16x8*>(zrow + kk * 32);

    f32x4 acc[8];
#pragma unroll
    for (int ct = 0; ct < 8; ++ct) acc[ct] = (f32x4){0.f, 0.f, 0.f, 0.f};

#pragma unroll
    for (int kk = 0; kk < 4; ++kk) {
#pragma unroll
        for (int ct = 0; ct < 8; ++ct) {
            const int j = ct * 16 + row;
            const int slot = (j * 16 + kk * 4 + q) ^ (j & 7);
            const bf16x8 b = *reinterpret_cast<const bf16x8*>(
                reinterpret_cast<char*>(w1s) + slot * 16);
            acc[ct] = __builtin_amdgcn_mfma_f32_16x16x32_bf16(
                a[kk], b, acc[ct], 0, 0, 0);
        }
    }

    float local = 0.0f;
#pragma unroll
    for (int ct = 0; ct < 8; ++ct) {
        const int j = ct * 16 + row;
        const float b1j = b1[j];
        const float w2j = W2[j];
#pragma unroll
        for (int r = 0; r < 4; ++r) {
            const int nd = node_base + q * 4 + r;
            if (nd < N_NODES)
                local += fast_tanh(acc[ct][r] + b1j) * w2j;
        }
    }
    for (int off = 32; off > 0; off >>= 1)
        local += __shfl_xor(local, off);
    if (l == 0) red[wv] = local;
    __syncthreads();
    if (tid == 0)
        atomicAdd(&wacc[m], red[0] + red[1] + red[2] + red[3]);
}

// ---------------------------------------------------------------------------
// K8: softmax over 3 scores + beta-weighted sum (bf16 z -> fp32 out).
__global__ __launch_bounds__(256) void final_kernel(
        const ushort* __restrict__ zb, const float* __restrict__ wacc,
        float* __restrict__ out) {
    const int g = blockIdx.x * 256 + threadIdx.x;      // 8-dim group, exact grid
    const float invN = 1.0f / (float)N_NODES;
    const float w0 = wacc[0] * invN, w1 = wacc[1] * invN, w2 = wacc[2] * invN;
    const float mx = fmaxf(w0, fmaxf(w1, w2));
    const float e0 = expf(w0 - mx), e1 = expf(w1 - mx), e2 = expf(w2 - mx);
    const float inv = 1.0f / (e0 + e1 + e2);
    const float beta[3] = {e0 * inv, e1 * inv, e2 * inv};
    float a[8] = {};
#pragma unroll
    for (int m = 0; m < N_META; ++m) {
        const uint4 v = reinterpret_cast<const uint4*>(zb)[
            (size_t)m * (N_NODES * DIM / 8) + g];
        const float bm = beta[m];
        a[0] = fmaf(bflo(v.x), bm, a[0]); a[1] = fmaf(bfhi(v.x), bm, a[1]);
        a[2] = fmaf(bflo(v.y), bm, a[2]); a[3] = fmaf(bfhi(v.y), bm, a[3]);
        a[4] = fmaf(bflo(v.z), bm, a[4]); a[5] = fmaf(bfhi(v.z), bm, a[5]);
        a[6] = fmaf(bflo(v.w), bm, a[6]); a[7] = fmaf(bfhi(v.w), bm, a[7]);
    }
    float4 o0 = {a[0], a[1], a[2], a[3]};
    float4 o1 = {a[4], a[5], a[6], a[7]};
    reinterpret_cast<float4*>(out)[(size_t)g * 2 + 0] = o0;
    reinterpret_cast<float4*>(out)[(size_t)g * 2 + 1] = o1;
}

extern "C" void kernel_launch(void* const* d_in, const int* in_sizes, int n_in,
                              void* d_out, int out_size, void* d_ws, size_t ws_size,
                              hipStream_t stream) {
    const float* h    = (const float*)d_in[0];
    const int*  edges = (const int*)d_in[1];
    const float* W1   = (const float*)d_in[2];
    const float* b1   = (const float*)d_in[3];
    const float* W2   = (const float*)d_in[4];
    float* out = (float*)d_out;

    // ws (~89MB): zb bf16 [38.4MB] region hosts pairs[19.2MB]+partials[19.2MB]
    // early (both dead before gather writes zb) | hbm (3 pre-scaled bf16
    // tables, 38.4MB) | csr | row_off | nsrc | bh/chunk_base | small
    char* p = (char*)d_ws;
    ushort* zb      = (ushort*)p;
    uint*  pairs    = (uint*)p;
    uint*  partials = (uint*)(p + (size_t)N_META * N_EDGES * 4);
    p += (size_t)N_META * N_NODES * DIM * 2;
    ushort* hbm     = (ushort*)p; p += (size_t)N_META * N_NODES * DIM * 2;
    ushort* csr     = (ushort*)p; p += (size_t)N_META * N_EDGES * 2;
    int* row_off    = (int*)p;    p += ((size_t)N_META * (N_NODES + 1) + 1) * 4;
    float* nsrc     = (float*)p;  p += (size_t)N_META * N_NODES * 4;
    float* wacc     = (float*)p;  p += 16 * 4;
    uint* bhout     = (uint*)p;   p += (size_t)N_META * OCH * NBKT * 4;
    int* chunk_base = (int*)p;    p += (size_t)N_META * OCH * NBKT * 4;
    int* bucket_off = (int*)p;    p += (size_t)N_META * (NBKT + 1) * 4 + 4;
    ushort* W1T     = (ushort*)p; p += (size_t)DIM * DIM * 2;

    hipMemsetAsync(wacc, 0, 16 * 4, stream);

    prep_kernel<<<dim3(PREP_A + W1C_B), 256, 0, stream>>>(
        edges, W1, bhout, partials, W1T);
    scan_nsrc_kernel<<<dim3(N_META + (N_META * N_NODES + 255) / 256), 256, 0, stream>>>(
        bhout, bucket_off, chunk_base, row_off, partials, nsrc);
    scale_kernel<<<dim3(N_NODES * DIM / 4 / 256), 256, 0, stream>>>(h, nsrc, hbm);
    bin_kernel<<<dim3(OCH, N_META), 256, 0, stream>>>(edges, chunk_base, pairs);
    csr_kernel<<<dim3(NBKT, N_META), 256, 0, stream>>>(pairs, bucket_off, row_off, csr);
    gather_kernel<<<dim3(N_NODES / 4, N_META), 256, 0, stream>>>(
        hbm, csr, row_off, zb);
    attn_kernel<<<dim3(AT_NBLK, N_META), 256, 0, stream>>>(zb, W1T, b1, W2, wacc);
    final_kernel<<<dim3(N_NODES * DIM / 8 / 256), 256, 0, stream>>>(zb, wacc, out);
}

// Round 10
// 373.400 us; speedup vs baseline: 1.0629x; 1.0228x over previous
//
#include <hip/hip_runtime.h>
#include <cstdint>
#include <cstddef>

typedef unsigned int  uint;
typedef unsigned short ushort;
typedef short bf16x8 __attribute__((ext_vector_type(8)));
typedef float f32x4  __attribute__((ext_vector_type(4)));

#define N_NODES 50000
#define N_EDGES 1600000
#define N_META  3
#define DIM     128

#define BKT       256                 // dst nodes per bucket
#define NBKT      196                 // ceil(N_NODES / BKT)
#define CSR_CAP   10240               // bucket mean 8192, +22 sigma
#define OCH       128                 // edge chunks per metapath
#define EPC       (N_EDGES / OCH)     // 12500 edges per chunk
#define OWORDS    12500               // 50000 nodes / 4 per uint (byte-packed)
#define PREP_A    (N_META * OCH)      // 384 hist blocks
#define W1C_B     4                   // W1 fp32 -> bf16 transpose
#define SCALE_B   6250                // scale role blocks (N_NODES*DIM/4/256)

#define AT_TILE   64                  // attn: nodes per block (4 waves x 16)
#define AT_NBLK   782                 // ceil(N_NODES / AT_TILE)

__device__ __forceinline__ uint bf16rne(float f) {
    const uint u = __float_as_uint(f);
    return (u + 0x7FFFu + ((u >> 16) & 1u)) >> 16;
}
__device__ __forceinline__ float bflo(uint p) { return __uint_as_float(p << 16); }
__device__ __forceinline__ float bfhi(uint p) { return __uint_as_float(p & 0xFFFF0000u); }
__device__ __forceinline__ float fast_tanh(float x) {
    const float e = __expf(2.0f * x);
    return 1.0f - 2.0f / (e + 1.0f);
}

// ---------------------------------------------------------------------------
// K1: prep.
//   [0, PREP_A)   : block = (m, chunk of 12.5K edges). Byte-packed src
//                   out-degree hist (50KB LDS) + dst bucket hist. Bucket hist
//                   is BOTH stored per (m,chunk) (bin derives its cursors from
//                   it, no histogram pass) AND atomically merged into
//                   bucket_cnt (so scan has no serial 128-chunk loops).
//   [.., +W1C_B)  : W1 fp32 [k][j] -> W1T bf16 [j][k]
__global__ __launch_bounds__(256) void prep_kernel(
        const int* __restrict__ edges, const float* __restrict__ W1,
        uint* __restrict__ bhout, int* __restrict__ bucket_cnt,
        uint* __restrict__ partials, ushort* __restrict__ W1T) {
    __shared__ __align__(16) uint sh[OWORDS];   // 50.0KB byte-packed out-degree
    __shared__ uint bh[NBKT];                   // bucket hist
    const int blk = blockIdx.x;
    if (blk < PREP_A) {
        const int m = blk >> 7, c = blk & 127;
        uint4* sh4 = reinterpret_cast<uint4*>(sh);
        for (int j = threadIdx.x; j < OWORDS / 4; j += 256)
            sh4[j] = make_uint4(0u, 0u, 0u, 0u);
        for (int j = threadIdx.x; j < NBKT; j += 256) bh[j] = 0;
        __syncthreads();
        const int* src = edges + (size_t)(2 * m) * N_EDGES;
        const int* dst = edges + (size_t)(2 * m + 1) * N_EDGES;
        const int beg = c * EPC;
        for (int i = beg + 4 * threadIdx.x; i + 4 <= beg + EPC; i += 1024) {
            const uint4 s4 = *reinterpret_cast<const uint4*>(src + i);
            const uint4 d4 = *reinterpret_cast<const uint4*>(dst + i);
            atomicAdd(&sh[s4.x >> 2], 1u << (8 * (s4.x & 3)));
            atomicAdd(&sh[s4.y >> 2], 1u << (8 * (s4.y & 3)));
            atomicAdd(&sh[s4.z >> 2], 1u << (8 * (s4.z & 3)));
            atomicAdd(&sh[s4.w >> 2], 1u << (8 * (s4.w & 3)));
            atomicAdd(&bh[d4.x >> 8], 1u);
            atomicAdd(&bh[d4.y >> 8], 1u);
            atomicAdd(&bh[d4.z >> 8], 1u);
            atomicAdd(&bh[d4.w >> 8], 1u);
        }
        __syncthreads();
        uint4* outp4 = reinterpret_cast<uint4*>(
            partials + (size_t)(m * OCH + c) * OWORDS);
        for (int j = threadIdx.x; j < OWORDS / 4; j += 256) outp4[j] = sh4[j];
        uint* bo = bhout + (size_t)(m * OCH + c) * NBKT;
        for (int j = threadIdx.x; j < NBKT; j += 256) {
            const uint v = bh[j];
            bo[j] = v;
            if (v) atomicAdd(&bucket_cnt[m * NBKT + j], (int)v);
        }
    } else {
        // W1T[j][k] = bf16(W1[k][j]); writes coalesced, reads strided (L2-hot)
        const int base = (blk - PREP_A) * (DIM * DIM / W1C_B);
        for (int o = base + threadIdx.x; o < base + DIM * DIM / W1C_B; o += 256) {
            const int j = o >> 7, k = o & 127;
            W1T[o] = (ushort)bf16rne(W1[k * DIM + j]);
        }
    }
}

// ---------------------------------------------------------------------------
// K2: scan.
//   [0, N_META)   : 196-element Hillis-Steele over bucket_cnt -> bucket_off.
//                   (No per-chunk loops -- those moved to bin's redundant
//                   column prefix, which is wide and latency-hidden.)
//   [N_META, ..)  : nsrc = rsqrt(out_deg) from byte-packed partials.
__global__ __launch_bounds__(256) void scan_nsrc_kernel(
        const int* __restrict__ bucket_cnt, int* __restrict__ bucket_off,
        int* __restrict__ row_off, const uint* __restrict__ partials,
        float* __restrict__ nsrc) {
    const int blk = blockIdx.x;
    if (blk < N_META) {
        __shared__ int sc[256];
        const int m = blk, t = threadIdx.x;
        const int v = (t < NBKT) ? bucket_cnt[m * NBKT + t] : 0;
        sc[t] = v;
        __syncthreads();
        for (int off = 1; off < 256; off <<= 1) {
            const int tt = (t >= off) ? sc[t - off] : 0;
            __syncthreads();
            sc[t] += tt;
            __syncthreads();
        }
        const int excl = sc[t] - v;
        if (t < NBKT) bucket_off[m * (NBKT + 1) + t] = excl;
        if (t == 0) {
            bucket_off[m * (NBKT + 1) + NBKT] = N_EDGES;
            row_off[m * (N_NODES + 1) + N_NODES] = N_EDGES;
        }
    } else {
        const int i = (blk - N_META) * 256 + threadIdx.x;
        if (i < N_META * N_NODES) {
            const int m = i / N_NODES, node = i - m * N_NODES;
            const int q = node >> 2, s8 = 8 * (node & 3);
            int s = 0;
#pragma unroll 8
            for (int c = 0; c < OCH; ++c)
                s += (partials[(size_t)(m * OCH + c) * OWORDS + q] >> s8) & 0xFF;
            nsrc[i] = rsqrtf(fmaxf((float)s, 1.0f));
        }
    }
}

// ---------------------------------------------------------------------------
// K3: merged mid kernel (both roles depend only on scan; one launch).
//   [0, PREP_A)   : bin = single scatter pass. Each block derives its own
//                   cursors: cur[b] = bucket_off[b] + sum_{c'<c} bhout[c'][b]
//                   (coalesced L2-hot reads, latency-hidden across 384 blocks).
//   [.., +SCALE_B): hbm[m][n][d] = bf16(h[n][d] * nsrc[m][n]).
__global__ __launch_bounds__(256) void bin_scale_kernel(
        const int* __restrict__ edges, const uint* __restrict__ bhout,
        const int* __restrict__ bucket_off, const float* __restrict__ h,
        const float* __restrict__ nsrc, uint* __restrict__ pairs,
        ushort* __restrict__ hbm) {
    const int blk = blockIdx.x;
    if (blk < PREP_A) {
        const int m = blk >> 7, c = blk & 127;
        __shared__ int cur[NBKT];
        for (int j = threadIdx.x; j < NBKT; j += 256) {
            int base = bucket_off[m * (NBKT + 1) + j];
            for (int cc = 0; cc < c; ++cc)
                base += (int)bhout[(size_t)(m * OCH + cc) * NBKT + j];
            cur[j] = base;
        }
        __syncthreads();
        const int* src = edges + (size_t)(2 * m) * N_EDGES;
        const int* dst = edges + (size_t)(2 * m + 1) * N_EDGES;
        const int beg = c * EPC;
        uint* pm = pairs + (size_t)m * N_EDGES;
        for (int i = beg + 4 * threadIdx.x; i + 4 <= beg + EPC; i += 1024) {
            const uint4 s4 = *reinterpret_cast<const uint4*>(src + i);
            const uint4 d4 = *reinterpret_cast<const uint4*>(dst + i);
            int p0 = atomicAdd(&cur[d4.x >> 8], 1);
            pm[p0] = (d4.x << 16) | s4.x;
            int p1 = atomicAdd(&cur[d4.y >> 8], 1);
            pm[p1] = (d4.y << 16) | s4.y;
            int p2 = atomicAdd(&cur[d4.z >> 8], 1);
            pm[p2] = (d4.z << 16) | s4.z;
            int p3 = atomicAdd(&cur[d4.w >> 8], 1);
            pm[p3] = (d4.w << 16) | s4.w;
        }
    } else {
        const int i = (blk - PREP_A) * 256 + threadIdx.x;  // float4 idx, exact
        const int node = i >> 5;                  // DIM/4 = 32 float4 per row
        const float4 v = reinterpret_cast<const float4*>(h)[i];
        uint2* o = reinterpret_cast<uint2*>(hbm);
#pragma unroll
        for (int m = 0; m < N_META; ++m) {
            const float n = nsrc[m * N_NODES + node];
            uint2 p;
            p.x = bf16rne(v.x * n) | (bf16rne(v.y * n) << 16);
            p.y = bf16rne(v.z * n) | (bf16rne(v.w * n) << 16);
            o[(size_t)m * (N_NODES * DIM / 4) + i] = p;
        }
    }
}

// ---------------------------------------------------------------------------
// K4: finalize CSR per bucket (ushort src ids).
__global__ __launch_bounds__(256) void csr_kernel(
        const uint* __restrict__ pairs, const int* __restrict__ bucket_off,
        int* __restrict__ row_off, ushort* __restrict__ csr) {
    const int b = blockIdx.x, m = blockIdx.y;
    const int node_base = b * BKT;
    const int nb = min(BKT, N_NODES - node_base);
    __shared__ uint stage[CSR_CAP];
    __shared__ int hist[BKT];
    __shared__ int sc[BKT];
    __shared__ int cur[BKT];
    hist[threadIdx.x] = 0;
    __syncthreads();
    const int beg = bucket_off[m * (NBKT + 1) + b];
    const int end = bucket_off[m * (NBKT + 1) + b + 1];
    const int cnt = end - beg;
    const uint* pm = pairs + (size_t)m * N_EDGES + beg;
    for (int i = threadIdx.x; i < cnt; i += 256) {
        const uint p = pm[i];
        if (i < CSR_CAP) stage[i] = p;
        atomicAdd(&hist[(int)(p >> 16) - node_base], 1);
    }
    __syncthreads();
    const int v = hist[threadIdx.x];
    sc[threadIdx.x] = v;
    __syncthreads();
    for (int off = 1; off < BKT; off <<= 1) {
        const int t = (threadIdx.x >= off) ? sc[threadIdx.x - off] : 0;
        __syncthreads();
        sc[threadIdx.x] += t;
        __syncthreads();
    }
    const int excl = sc[threadIdx.x] - v;
    cur[threadIdx.x] = beg + excl;
    if (threadIdx.x < nb)
        row_off[m * (N_NODES + 1) + node_base + threadIdx.x] = beg + excl;
    __syncthreads();
    ushort* cm = csr + (size_t)m * N_EDGES;
    for (int i = threadIdx.x; i < cnt; i += 256) {
        const uint p = (i < CSR_CAP) ? stage[i] : pm[i];
        const int dl = (int)(p >> 16) - node_base;
        const int pos = atomicAdd(&cur[dl], 1);
        cm[pos] = (ushort)(p & 0xFFFFu);
    }
}

// ---------------------------------------------------------------------------
// K5: gather. One wave per dst node; quarter-wave (16 lanes x uint4 = 256B)
// covers a full bf16 row, 4 edges/step, unroll-4 -> 16 edges in flight.
// Rows are pre-scaled by nsrc, so the loop is pure load+add. z stored bf16.
__global__ __launch_bounds__(256) void gather_kernel(
        const ushort* __restrict__ hbm, const ushort* __restrict__ csr,
        const int* __restrict__ row_off, ushort* __restrict__ zb) {
    const int m    = blockIdx.y;
    const int wave = threadIdx.x >> 6;
    const int lane = threadIdx.x & 63;
    const int q    = lane >> 4;              // edge slot 0..3
    const int c16  = lane & 15;              // dims 8*c16 .. 8*c16+7
    const int node = blockIdx.x * 4 + wave;
    const int* ro = row_off + m * (N_NODES + 1);
    const int beg = ro[node];
    const int end = ro[node + 1];
    const ushort* srcs = csr + (size_t)m * N_EDGES;
    const ushort* tab  = hbm + (size_t)m * N_NODES * DIM;
    float acc[8] = {};
    int j = beg;
    for (; j + 16 <= end; j += 16) {
        int s[4]; uint4 hv[4];
#pragma unroll
        for (int u = 0; u < 4; ++u) s[u] = srcs[j + 4 * u + q];
#pragma unroll
        for (int u = 0; u < 4; ++u)
            hv[u] = *reinterpret_cast<const uint4*>(tab + (size_t)s[u] * DIM + c16 * 8);
#pragma unroll
        for (int u = 0; u < 4; ++u) {
            acc[0] += bflo(hv[u].x); acc[1] += bfhi(hv[u].x);
            acc[2] += bflo(hv[u].y); acc[3] += bfhi(hv[u].y);
            acc[4] += bflo(hv[u].z); acc[5] += bfhi(hv[u].z);
            acc[6] += bflo(hv[u].w); acc[7] += bfhi(hv[u].w);
        }
    }
    for (; j + 4 <= end; j += 4) {
        const int s0 = srcs[j + q];
        const uint4 hv = *reinterpret_cast<const uint4*>(tab + (size_t)s0 * DIM + c16 * 8);
        acc[0] += bflo(hv.x); acc[1] += bfhi(hv.x);
        acc[2] += bflo(hv.y); acc[3] += bfhi(hv.y);
        acc[4] += bflo(hv.z); acc[5] += bfhi(hv.z);
        acc[6] += bflo(hv.w); acc[7] += bfhi(hv.w);
    }
    if (j + q < end) {
        const int s0 = srcs[j + q];
        const uint4 hv = *reinterpret_cast<const uint4*>(tab + (size_t)s0 * DIM + c16 * 8);
        acc[0] += bflo(hv.x); acc[1] += bfhi(hv.x);
        acc[2] += bflo(hv.y); acc[3] += bfhi(hv.y);
        acc[4] += bflo(hv.z); acc[5] += bfhi(hv.z);
        acc[6] += bflo(hv.w); acc[7] += bfhi(hv.w);
    }
#pragma unroll
    for (int k = 0; k < 8; ++k) {
        acc[k] += __shfl_xor(acc[k], 16);
        acc[k] += __shfl_xor(acc[k], 32);
    }
    if (lane < 16) {
        const float nd = rsqrtf(fmaxf((float)(end - beg), 1.0f));
        uint4 o;
        o.x = bf16rne(acc[0] * nd) | (bf16rne(acc[1] * nd) << 16);
        o.y = bf16rne(acc[2] * nd) | (bf16rne(acc[3] * nd) << 16);
        o.z = bf16rne(acc[4] * nd) | (bf16rne(acc[5] * nd) << 16);
        o.w = bf16rne(acc[6] * nd) | (bf16rne(acc[7] * nd) << 16);
        *reinterpret_cast<uint4*>(
            zb + ((size_t)m * N_NODES + node) * DIM + c16 * 8) = o;
    }
}

// ---------------------------------------------------------------------------
// K6: semantic attention via MFMA (16x16x32 bf16). A-frags straight from
// global; B-frags from XOR-swizzled LDS W1T. C: col=lane&15, row=(lane>>4)*4+r.
__global__ __launch_bounds__(256) void attn_kernel(
        const ushort* __restrict__ zb, const ushort* __restrict__ W1T,
        const float* __restrict__ b1, const float* __restrict__ W2,
        float* __restrict__ wacc) {
    const int m   = blockIdx.y;
    const int tid = threadIdx.x;
    const int wv  = tid >> 6;
    const int l   = tid & 63;
    __shared__ __align__(16) ushort w1s[DIM * DIM];   // swizzled [j][k] bf16
    __shared__ float red[4];

    {   // stage W1T with XOR swizzle on the 16B-slot index
        const uint4* g = reinterpret_cast<const uint4*>(W1T);
        for (int i = tid; i < DIM * DIM / 8; i += 256) {
            const int j = i >> 4;                      // 16 uint4 per j-row
            const int slot = i ^ (j & 7);
            *reinterpret_cast<uint4*>(
                reinterpret_cast<char*>(w1s) + slot * 16) = g[i];
        }
    }
    __syncthreads();

    const int node_base = blockIdx.x * AT_TILE + wv * 16;
    const int row = l & 15;                // node within tile / j within tile
    const int q   = l >> 4;                // k-chunk / C row-quad
    int nload = node_base + row;
    if (nload >= N_NODES) nload = N_NODES - 1;         // clamp; masked later
    const ushort* zrow = zb + ((size_t)m * N_NODES + nload) * DIM + q * 8;

    bf16x8 a[4];
#pragma unroll
    for (int kk = 0; kk < 4; ++kk)
        a[kk] = *reinterpret_cast<const bf16x8*>(zrow + kk * 32);

    f32x4 acc[8];
#pragma unroll
    for (int ct = 0; ct < 8; ++ct) acc[ct] = (f32x4){0.f, 0.f, 0.f, 0.f};

#pragma unroll
    for (int kk = 0; kk < 4; ++kk) {
#pragma unroll
        for (int ct = 0; ct < 8; ++ct) {
            const int j = ct * 16 + row;
            const int slot = (j * 16 + kk * 4 + q) ^ (j & 7);
            const bf16x8 b = *reinterpret_cast<const bf16x8*>(
                reinterpret_cast<char*>(w1s) + slot * 16);
            acc[ct] = __builtin_amdgcn_mfma_f32_16x16x32_bf16(
                a[kk], b, acc[ct], 0, 0, 0);
        }
    }

    float local = 0.0f;
#pragma unroll
    for (int ct = 0; ct < 8; ++ct) {
        const int j = ct * 16 + row;
        const float b1j = b1[j];
        const float w2j = W2[j];
#pragma unroll
        for (int r = 0; r < 4; ++r) {
            const int nd = node_base + q * 4 + r;
            if (nd < N_NODES)
                local += fast_tanh(acc[ct][r] + b1j) * w2j;
        }
    }
    for (int off = 32; off > 0; off >>= 1)
        local += __shfl_xor(local, off);
    if (l == 0) red[wv] = local;
    __syncthreads();
    if (tid == 0)
        atomicAdd(&wacc[m], red[0] + red[1] + red[2] + red[3]);
}

// ---------------------------------------------------------------------------
// K7: softmax over 3 scores + beta-weighted sum (bf16 z -> fp32 out).
__global__ __launch_bounds__(256) void final_kernel(
        const ushort* __restrict__ zb, const float* __restrict__ wacc,
        float* __restrict__ out) {
    const int g = blockIdx.x * 256 + threadIdx.x;      // 8-dim group, exact grid
    const float invN = 1.0f / (float)N_NODES;
    const float w0 = wacc[0] * invN, w1 = wacc[1] * invN, w2 = wacc[2] * invN;
    const float mx = fmaxf(w0, fmaxf(w1, w2));
    const float e0 = expf(w0 - mx), e1 = expf(w1 - mx), e2 = expf(w2 - mx);
    const float inv = 1.0f / (e0 + e1 + e2);
    const float beta[3] = {e0 * inv, e1 * inv, e2 * inv};
    float a[8] = {};
#pragma unroll
    for (int m = 0; m < N_META; ++m) {
        const uint4 v = reinterpret_cast<const uint4*>(zb)[
            (size_t)m * (N_NODES * DIM / 8) + g];
        const float bm = beta[m];
        a[0] = fmaf(bflo(v.x), bm, a[0]); a[1] = fmaf(bfhi(v.x), bm, a[1]);
        a[2] = fmaf(bflo(v.y), bm, a[2]); a[3] = fmaf(bfhi(v.y), bm, a[3]);
        a[4] = fmaf(bflo(v.z), bm, a[4]); a[5] = fmaf(bfhi(v.z), bm, a[5]);
        a[6] = fmaf(bflo(v.w), bm, a[6]); a[7] = fmaf(bfhi(v.w), bm, a[7]);
    }
    float4 o0 = {a[0], a[1], a[2], a[3]};
    float4 o1 = {a[4], a[5], a[6], a[7]};
    reinterpret_cast<float4*>(out)[(size_t)g * 2 + 0] = o0;
    reinterpret_cast<float4*>(out)[(size_t)g * 2 + 1] = o1;
}

extern "C" void kernel_launch(void* const* d_in, const int* in_sizes, int n_in,
                              void* d_out, int out_size, void* d_ws, size_t ws_size,
                              hipStream_t stream) {
    const float* h    = (const float*)d_in[0];
    const int*  edges = (const int*)d_in[1];
    const float* W1   = (const float*)d_in[2];
    const float* b1   = (const float*)d_in[3];
    const float* W2   = (const float*)d_in[4];
    float* out = (float*)d_out;

    // ws (~89MB): zb bf16 [38.4MB] region hosts pairs[19.2MB]+partials[19.2MB]
    // early (both dead before gather writes zb) | hbm (3 pre-scaled bf16
    // tables, 38.4MB) | csr | row_off | nsrc | wacc+bucket_cnt (memset
    // together) | bucket_off | bhout | W1T
    char* p = (char*)d_ws;
    ushort* zb      = (ushort*)p;
    uint*  pairs    = (uint*)p;
    uint*  partials = (uint*)(p + (size_t)N_META * N_EDGES * 4);
    p += (size_t)N_META * N_NODES * DIM * 2;
    ushort* hbm     = (ushort*)p; p += (size_t)N_META * N_NODES * DIM * 2;
    ushort* csr     = (ushort*)p; p += (size_t)N_META * N_EDGES * 2;
    int* row_off    = (int*)p;    p += ((size_t)N_META * (N_NODES + 1) + 1) * 4;
    float* nsrc     = (float*)p;  p += (size_t)N_META * N_NODES * 4;
    float* wacc     = (float*)p;  p += 16 * 4;
    int* bucket_cnt = (int*)p;    p += (size_t)N_META * NBKT * 4;
    int* bucket_off = (int*)p;    p += (size_t)N_META * (NBKT + 1) * 4 + 4;
    uint* bhout     = (uint*)p;   p += (size_t)N_META * OCH * NBKT * 4;
    ushort* W1T     = (ushort*)p; p += (size_t)DIM * DIM * 2;

    // zero wacc + bucket_cnt (contiguous)
    hipMemsetAsync(wacc, 0, (16 + (size_t)N_META * NBKT) * 4, stream);

    prep_kernel<<<dim3(PREP_A + W1C_B), 256, 0, stream>>>(
        edges, W1, bhout, bucket_cnt, partials, W1T);
    scan_nsrc_kernel<<<dim3(N_META + (N_META * N_NODES + 255) / 256), 256, 0, stream>>>(
        bucket_cnt, bucket_off, row_off, partials, nsrc);
    bin_scale_kernel<<<dim3(PREP_A + SCALE_B), 256, 0, stream>>>(
        edges, bhout, bucket_off, h, nsrc, pairs, hbm);
    csr_kernel<<<dim3(NBKT, N_META), 256, 0, stream>>>(pairs, bucket_off, row_off, csr);
    gather_kernel<<<dim3(N_NODES / 4, N_META), 256, 0, stream>>>(
        hbm, csr, row_off, zb);
    attn_kernel<<<dim3(AT_NBLK, N_META), 256, 0, stream>>>(zb, W1T, b1, W2, wacc);
    final_kernel<<<dim3(N_NODES * DIM / 8 / 256), 256, 0, stream>>>(zb, wacc, out);
}